// Round 14
// baseline (197.742 us; speedup 1.0000x reference)
//
#include <hip/hip_runtime.h>

constexpr int N_NODES = 50000;
constexpr int N_REL   = 4;
constexpr int EMBD    = 128;
constexpr int N_HEAD  = 4;
constexpr int HS      = 32;
constexpr int N_EDGE  = 400000;
constexpr int N_ROWS  = N_REL * N_NODES;        // 200000 segment rows
constexpr int N_SBLK  = 196;                    // scan blocks (1024 rows each)
constexpr int N_BIN   = 16;                     // degree bins (15 = deg>=15)

typedef __attribute__((ext_vector_type(8))) short bf16x8;
typedef __attribute__((ext_vector_type(4))) float f32x4;
typedef unsigned short ushort_t;
typedef unsigned int   uint_t;

__device__ __forceinline__ ushort_t f2b(float f) {
    unsigned int u = __float_as_uint(f);
    u += 0x7FFF + ((u >> 16) & 1);   // round-to-nearest-even
    return (ushort_t)(u >> 16);
}
__device__ __forceinline__ float lo_bf(uint_t u) {   // bf16 pair: low elem
    return __uint_as_float(u << 16);
}
__device__ __forceinline__ float hi_bf(uint_t u) {   // bf16 pair: high elem
    return __uint_as_float(u & 0xFFFF0000u);
}

// ---------------------------------------------------------------------------
// prep (fused): XB = bf16(x), HIST = 0, Ct = tokeys^T toqueries (per r,h),
// Mb = U·BD(tovals). KNOWN GOOD (r13).
// ---------------------------------------------------------------------------
__global__ __launch_bounds__(256) void prep_kernel(
    const float* __restrict__ x,
    const float* __restrict__ tk, const float* __restrict__ tq,
    const float* __restrict__ tv, const float* __restrict__ un,
    ushort_t* __restrict__ XB, int* __restrict__ HIST,
    ushort_t* __restrict__ Ct, ushort_t* __restrict__ Mb)
{
    int idx = blockIdx.x * 256 + threadIdx.x;      // grid 25320 = 6481920 threads
    if (idx < N_NODES * EMBD) {
        XB[idx] = f2b(x[idx]);
        if (idx < N_ROWS) HIST[idx] = 0;
    } else {
        int jj = idx - N_NODES * EMBD;             // < 81920
        if (jj < 16384) {
            int a = jj & 31, b = (jj >> 5) & 31, rh = jj >> 10;   // rh = r*4+h
            const float* tks = tk + rh * 1024;     // [s][a]
            const float* tqs = tq + rh * 1024;     // [s][b]
            float acc = 0.f;
            #pragma unroll
            for (int s = 0; s < 32; s++) acc += tks[s * 32 + a] * tqs[s * 32 + b];
            Ct[jj] = f2b(acc);                     // (rh*32 + b)*32 + a
        } else {
            int j  = jj - 16384;                   // Mb flat: [r][i][jc]
            int jc = j & 127, i = (j >> 7) & 127, r = j >> 14;
            int h = jc >> 5, k = jc & 31;
            const float* us  = un + ((size_t)(r * 128 + i)) * 128 + h * 32;
            const float* tvs = tv + (r * 4 + h) * 1024 + k;
            float acc = 0.f;
            #pragma unroll
            for (int s = 0; s < 32; s++) acc += us[s] * tvs[s * 32];
            Mb[j] = f2b(acc);
        }
    }
}

// ---------------------------------------------------------------------------
// MFMA projection: Kt[r][n][h*32+b] = sum_a Ct[r,h,b,a]*x[n,h*32+a].
// KNOWN GOOD (r12-13; fragment maps proven r5-13).
// ---------------------------------------------------------------------------
__global__ __launch_bounds__(512) void proj_mfma(
    const ushort_t* __restrict__ XB, const ushort_t* __restrict__ Ct,
    ushort_t* __restrict__ KT)
{
    __shared__ ushort_t xs[128 * 136];   // [node][k] bf16, stride 272B

    const int t    = threadIdx.x;        // 0..511
    const int lane = t & 63;
    const int w    = t >> 6;             // wave 0..7
    const int n0   = blockIdx.x * 128;

    {   // stage XB tile (bf16, 16B chunks)
        const uint4* x4 = (const uint4*)(XB + (size_t)n0 * 128);
        for (int idx = t; idx < 128 * 16; idx += 512) {
            int nn = idx >> 4, c = idx & 15;
            uint4 v = make_uint4(0, 0, 0, 0);
            if (n0 + nn < N_NODES) v = x4[idx];
            *(uint4*)&xs[nn * 136 + c * 8] = v;
        }
    }
    __syncthreads();

    const int row  = lane & 15;     // A node-row / B col / D col
    const int kg   = lane >> 4;     // k-group (8 elems each)
    const int rgrp = lane >> 4;     // D row-group

    #pragma unroll 1
    for (int r = 0; r < N_REL; r++) {
        f32x4 acc[8];
        #pragma unroll
        for (int f = 0; f < 8; f++) {
            const int h = f >> 1;
            bf16x8 a = *(const bf16x8*)&xs[(w * 16 + row) * 136 + h * 32 + kg * 8];
            const ushort_t* bp = Ct + (((r * 4 + h) * 32 + (f & 1) * 16 + row) * 32) + kg * 8;
            bf16x8 b = *(const bf16x8*)bp;
            acc[f] = __builtin_amdgcn_mfma_f32_16x16x32_bf16(
                         a, b, (f32x4){0.f, 0.f, 0.f, 0.f}, 0, 0, 0);
        }
        #pragma unroll
        for (int f = 0; f < 8; f++) {
            #pragma unroll
            for (int reg = 0; reg < 4; reg++) {
                int n = n0 + w * 16 + rgrp * 4 + reg;
                if (n < N_NODES)
                    KT[((size_t)r * N_NODES + n) * 128 + f * 16 + row] = f2b(acc[f][reg]);
            }
        }
    }
}

// ---------------------------------------------------------------------------
// CSR build: histogram -> 3-phase deterministic scan -> scatter. KNOWN GOOD.
// scan_p3 additionally emits per-block degree-bin histograms BH[block][16]
// (v[k] already holds each row's degree — zero extra memory passes).
// ---------------------------------------------------------------------------
__global__ __launch_bounds__(256) void hist_kernel(
    const int* __restrict__ esub, const int* __restrict__ epred, int* __restrict__ HIST)
{
    int e = blockIdx.x * 256 + threadIdx.x;
    if (e < N_EDGE) atomicAdd(&HIST[epred[e] * N_NODES + esub[e]], 1);
}

__global__ __launch_bounds__(256) void scan_p1(      // per-block totals
    const int* __restrict__ HIST, int* __restrict__ SUMS)
{
    int b = blockIdx.x, t = threadIdx.x;
    int base = b * 1024 + t * 4;
    int s = 0;
    #pragma unroll
    for (int k = 0; k < 4; k++) if (base + k < N_ROWS) s += HIST[base + k];
    __shared__ int red[256];
    red[t] = s; __syncthreads();
    for (int st = 128; st > 0; st >>= 1) {
        if (t < st) red[t] += red[t + st];
        __syncthreads();
    }
    if (t == 0) SUMS[b] = red[0];
}

__global__ __launch_bounds__(256) void scan_p2(      // scan the 196 totals
    const int* __restrict__ SUMS, int* __restrict__ SOFF, int* __restrict__ OFFS)
{
    int t = threadIdx.x;
    __shared__ int sh[256];
    int o = (t < N_SBLK) ? SUMS[t] : 0;
    sh[t] = o; __syncthreads();
    for (int st = 1; st < 256; st <<= 1) {
        int v = (t >= st) ? sh[t - st] : 0;
        __syncthreads();
        sh[t] += v;
        __syncthreads();
    }
    if (t < N_SBLK) SOFF[t] = sh[t] - o;             // exclusive
    if (t == 0)  OFFS[N_ROWS] = sh[255];             // total == N_EDGE
}

__global__ __launch_bounds__(256) void scan_p3(      // full exclusive scan (+CURSOR +BH)
    const int* __restrict__ HIST, const int* __restrict__ SOFF,
    int* __restrict__ OFFS, int* __restrict__ CURSOR, int* __restrict__ BH)
{
    int b = blockIdx.x, t = threadIdx.x;
    int base = b * 1024 + t * 4;
    int v[4], tot = 0;
    #pragma unroll
    for (int k = 0; k < 4; k++) {
        v[k] = (base + k < N_ROWS) ? HIST[base + k] : 0;
        tot += v[k];
    }
    __shared__ int sh[256];
    __shared__ int bh[N_BIN];
    if (t < N_BIN) bh[t] = 0;
    sh[t] = tot; __syncthreads();                    // sync also publishes bh zeros
    #pragma unroll
    for (int k = 0; k < 4; k++) {
        if (base + k < N_ROWS) atomicAdd(&bh[min(v[k], 15)], 1);
    }
    for (int st = 1; st < 256; st <<= 1) {
        int q = (t >= st) ? sh[t - st] : 0;
        __syncthreads();
        sh[t] += q;
        __syncthreads();
    }
    int run = SOFF[b] + (sh[t] - tot);
    #pragma unroll
    for (int k = 0; k < 4; k++) {
        if (base + k < N_ROWS) { OFFS[base + k] = run; CURSOR[base + k] = run; run += v[k]; }
    }
    __syncthreads();                                 // bh atomics done (covered by loop syncs too)
    if (t < N_BIN) BH[b * N_BIN + t] = bh[t];
}

__global__ __launch_bounds__(256) void scatter_kernel(
    const int* __restrict__ esub, const int* __restrict__ epred, const int* __restrict__ eobj,
    int* __restrict__ CURSOR, int* __restrict__ OBJS)
{
    int e = blockIdx.x * 256 + threadIdx.x;
    if (e < N_EDGE) {
        int row = epred[e] * N_NODES + esub[e];
        int pos = atomicAdd(&CURSOR[row], 1);
        OBJS[pos] = eobj[e];                       // store obj, not edge id
    }
}

// ---------------------------------------------------------------------------
// Degree-bin scan: exclusive offsets over (bin-major, block-minor) order of
// BH -> BOFF[block][bin]. 3136 values, one block. Deterministic.
// ---------------------------------------------------------------------------
__global__ __launch_bounds__(256) void bin_scan(
    const int* __restrict__ BH, int* __restrict__ BOFF)
{
    constexpr int TOT = N_SBLK * N_BIN;             // 3136
    __shared__ int vals[TOT];
    __shared__ int part[256];
    int t = threadIdx.x;
    for (int i = t; i < TOT; i += 256) {
        int bin = i / N_SBLK, blk = i % N_SBLK;     // bin-major order
        vals[i] = BH[blk * N_BIN + bin];
    }
    __syncthreads();
    int c0 = t * 13;                                // 13*256 = 3328 >= 3136
    int s = 0;
    for (int k = 0; k < 13; k++) { int i = c0 + k; if (i < TOT) s += vals[i]; }
    part[t] = s; __syncthreads();
    for (int st = 1; st < 256; st <<= 1) {
        int v = (t >= st) ? part[t - st] : 0;
        __syncthreads();
        part[t] += v;
        __syncthreads();
    }
    int run = (t > 0) ? part[t - 1] : 0;            // exclusive chunk base
    for (int k = 0; k < 13; k++) {
        int i = c0 + k;
        if (i < TOT) {
            int bin = i / N_SBLK, blk = i % N_SBLK;
            int v = vals[i];
            BOFF[blk * N_BIN + bin] = run;
            run += v;
        }
    }
}

// ---------------------------------------------------------------------------
// Degree-bin scatter: ROWIDX = row ids grouped by degree bin. Per-block LDS
// cursors from BOFF. Row order within a bin is irrelevant (per-row results
// are independent of which wave processes them).
// ---------------------------------------------------------------------------
__global__ __launch_bounds__(256) void bin_scatter(
    const int* __restrict__ OFFS, const int* __restrict__ BOFF, int* __restrict__ ROWIDX)
{
    __shared__ int cur[N_BIN];
    int b = blockIdx.x, t = threadIdx.x;
    if (t < N_BIN) cur[t] = BOFF[b * N_BIN + t];
    __syncthreads();
    int base = b * 1024 + t * 4;
    #pragma unroll
    for (int k = 0; k < 4; k++) {
        int i = base + k;
        if (i < N_ROWS) {
            int deg = OFFS[i + 1] - OFFS[i];
            int pos = atomicAdd(&cur[min(deg, 15)], 1);
            ROWIDX[pos] = i;
        }
    }
}

// ---------------------------------------------------------------------------
// FUSED dot+softmax+aggregate in X-SPACE, 4 rows/wave taken from the
// DEGREE-SORTED ROWIDX: all 4 chains stay live until simultaneous drain
// (iterations ~= avg degree, not max; slot waste ~0 — r13's loop ran
// E[max of 4 Poisson(2)] ~= 4 iters carrying ~2 live edges).
// Per edge: ONE 256B gather of x_obj (L2/L3-resident XB) feeds BOTH the
// bilinear dot (vs row-local Kt) and the aggregation. Per-q work guarded by
// d[q] (uniform-in-value across the wave -> exec all-on/off, shfl-safe).
// ---------------------------------------------------------------------------
__global__ __launch_bounds__(256) void agg_fused(
    const int* __restrict__ ROWIDX, const int* __restrict__ OFFS,
    const int* __restrict__ OBJS,
    const uint_t* __restrict__ KT64, const uint_t* __restrict__ XB64,
    uint_t* __restrict__ AGG64)
{
    const int t    = threadIdx.x;
    const int lane = t & 63;
    const int s0   = (blockIdx.x * 4 + (t >> 6)) * 4;   // grid 12500: 200000 rows

    int rows[4], bq[4], eq[4], it[4];
    float klo[4], khi[4], aclo[4], achi[4], seg[4];
    #pragma unroll
    for (int q = 0; q < 4; q++) {
        rows[q] = ROWIDX[s0 + q];
        bq[q] = OFFS[rows[q]];
        eq[q] = OFFS[rows[q] + 1];
        it[q] = bq[q];
        aclo[q] = 0.f; achi[q] = 0.f; seg[q] = 0.f;
        klo[q] = 0.f;  khi[q] = 0.f;
        if (bq[q] < eq[q]) {
            uint_t ku = KT64[(unsigned)rows[q] * 64u + lane];
            klo[q] = lo_bf(ku); khi[q] = hi_bf(ku);
        }
    }

    while (it[0] < eq[0] || it[1] < eq[1] || it[2] < eq[2] || it[3] < eq[3]) {
        uint_t xu[4];
        bool   d[4];
        #pragma unroll
        for (int q = 0; q < 4; q++) {               // issue all live gathers first
            d[q]  = it[q] < eq[q];
            xu[q] = 0;
            if (d[q]) xu[q] = XB64[(unsigned)OBJS[it[q]] * 64u + lane];
        }
        #pragma unroll
        for (int q = 0; q < 4; q++) {
            if (d[q]) {                             // uniform-in-value guard
                float p = klo[q] * lo_bf(xu[q]) + khi[q] * hi_bf(xu[q]);
                #pragma unroll
                for (int m = 1; m < 16; m <<= 1) p += __shfl_xor(p, m, 64);
                float ex = __expf(p);
                aclo[q] += ex * lo_bf(xu[q]);
                achi[q] += ex * hi_bf(xu[q]);
                seg[q]  += ex;
                it[q]++;
            }
        }
    }

    #pragma unroll
    for (int q = 0; q < 4; q++) {
        uint_t o = 0u;
        if (bq[q] < eq[q]) {
            float inv = 1.0f / seg[q];
            o = (uint_t)f2b(aclo[q] * inv) | ((uint_t)f2b(achi[q] * inv) << 16);
        }
        AGG64[(unsigned)rows[q] * 64u + lane] = o;
    }
}

// ---------------------------------------------------------------------------
// out[n][i] = relu( sum_r sum_j M[r][i][j] * AGGX[r][n][j] )  — bf16 MFMA,
// fp32 accum. KNOWN GOOD (rounds 5-13); B = Mb (U·BD(tovals)).
// ---------------------------------------------------------------------------
__global__ __launch_bounds__(256) void unify_mfma(
    const ushort_t* __restrict__ AGG,
    const ushort_t* __restrict__ Ub, float* __restrict__ out)
{
    __shared__ ushort_t As[64 * 136];    // A tile: [node][k] bf16
    __shared__ ushort_t Bs[128 * 136];   // B tile: [i][k] bf16

    const int t    = threadIdx.x;
    const int lane = t & 63;
    const int w    = t >> 6;
    const int n0   = blockIdx.x * 64;

    f32x4 acc[8];
    #pragma unroll
    for (int f = 0; f < 8; f++) acc[f] = (f32x4){0.f, 0.f, 0.f, 0.f};

    for (int r = 0; r < N_REL; r++) {
        __syncthreads();

        {   // stage A: AGG[r][n0..n0+63][0..127] plain bf16 copy (16B chunks)
            const uint4* a4 = (const uint4*)(AGG + ((size_t)r * N_NODES + n0) * 128);
            for (int idx = t; idx < 64 * 16; idx += 256) {
                int nn = idx >> 4, c = idx & 15;
                uint4 v = make_uint4(0, 0, 0, 0);
                if (n0 + nn < N_NODES) v = a4[idx];
                *(uint4*)&As[nn * 136 + c * 8] = v;
            }
        }
        {   // stage B: Mb[r] straight copy (L2-hot)
            const uint4* u4 = (const uint4*)(Ub + (size_t)r * 128 * 128);
            for (int idx = t; idx < 128 * 16; idx += 256) {
                int i = idx >> 4, c = idx & 15;
                *(uint4*)&Bs[i * 136 + c * 8] = u4[idx];
            }
        }
        __syncthreads();

        const int row = lane & 15;     // A row / B col
        const int kg  = lane >> 4;     // k-group
        #pragma unroll
        for (int ks = 0; ks < 4; ks++) {
            const int kofs = ks * 32 + kg * 8;
            bf16x8 a = *(const bf16x8*)&As[(w * 16 + row) * 136 + kofs];
            #pragma unroll
            for (int f = 0; f < 8; f++) {
                bf16x8 b = *(const bf16x8*)&Bs[(f * 16 + row) * 136 + kofs];
                acc[f] = __builtin_amdgcn_mfma_f32_16x16x32_bf16(a, b, acc[f], 0, 0, 0);
            }
        }
    }

    const int col  = lane & 15;
    const int rgrp = lane >> 4;
    #pragma unroll
    for (int f = 0; f < 8; f++) {
        #pragma unroll
        for (int reg = 0; reg < 4; reg++) {
            int n = n0 + w * 16 + rgrp * 4 + reg;
            if (n < N_NODES)
                out[(size_t)n * 128 + f * 16 + col] = fmaxf(acc[f][reg], 0.f);
        }
    }
}

extern "C" void kernel_launch(void* const* d_in, const int* in_sizes, int n_in,
                              void* d_out, int out_size, void* d_ws, size_t ws_size,
                              hipStream_t stream)
{
    const float* x  = (const float*)d_in[0];
    const float* tk = (const float*)d_in[1];
    const float* tq = (const float*)d_in[2];
    const float* tv = (const float*)d_in[3];
    const float* un = (const float*)d_in[4];
    const int* esub  = (const int*)d_in[5];
    const int* epred = (const int*)d_in[6];
    const int* eobj  = (const int*)d_in[7];
    float* out = (float*)d_out;

    // Workspace layout (bytes), r12/13 base + binning buffers, top ~119.4MB:
    //   KT:   [R][N][128] bf16 (Kt = Ct-projected x)     @ 0            (51,200,000)
    //   XB:   [N][128] bf16 (x cast — the gather target) @ 51,200,000   (12,800,000)
    //   AGG:  [R*N][128] bf16 (x-space aggregates)       @ 64,000,000   (51,200,000)
    //   HIST/CURSOR: [200000] int                        @ 115,200,000  (   800,000)
    //   SUMS: [196] int (pad 4096)                       @ 116,000,000  (     4,096)
    //   SOFF: [196] int (pad 4096)                       @ 116,004,096  (     4,096)
    //   OFFS: [200001] int                               @ 116,008,192  (   800,004 pad)
    //   OBJS: [400000] int                               @ 116,816,000  ( 1,600,000)
    //   Mb:   [R][128][128] bf16 (U·BD(tovals))          @ 118,416,000  (   131,072)
    //   Ct:   [R][H][32][32] bf16 (K^T Q bilinear)       @ 118,547,072  (    32,768)
    //   ROWIDX: [200000] int (degree-sorted row ids)     @ 118,579,840  (   800,000)
    //   BH:   [196][16] int                              @ 119,379,840  (    16,384 pad)
    //   BOFF: [196][16] int                              @ 119,396,224  (    16,384 pad)
    char* ws = (char*)d_ws;
    ushort_t* KT    = (ushort_t*)(ws);
    ushort_t* XB    = (ushort_t*)(ws + 51200000);
    ushort_t* AGG   = (ushort_t*)(ws + 64000000);
    int*      HIST  = (int*)     (ws + 115200000);   // doubles as CURSOR
    int*      SUMS  = (int*)     (ws + 116000000);
    int*      SOFF  = (int*)     (ws + 116004096);
    int*      OFFS  = (int*)     (ws + 116008192);
    int*      OBJS  = (int*)     (ws + 116816000);
    ushort_t* Mb    = (ushort_t*)(ws + 118416000);
    ushort_t* Ct    = (ushort_t*)(ws + 118547072);
    int*      ROWIDX= (int*)     (ws + 118579840);
    int*      BH    = (int*)     (ws + 119379840);
    int*      BOFF  = (int*)     (ws + 119396224);

    // prep (fused): x cast + HIST zero + Ct/Mb small-matrix products
    prep_kernel<<<(N_NODES * EMBD + 81920) / 256, 256, 0, stream>>>(
        x, tk, tq, tv, un, XB, HIST, Ct, Mb);

    // CSR build (+ per-block degree-bin histograms in scan_p3)
    hist_kernel<<<(N_EDGE + 255) / 256, 256, 0, stream>>>(esub, epred, HIST);
    scan_p1<<<N_SBLK, 256, 0, stream>>>(HIST, SUMS);
    scan_p2<<<1, 256, 0, stream>>>(SUMS, SOFF, OFFS);
    scan_p3<<<N_SBLK, 256, 0, stream>>>(HIST, SOFF, OFFS, HIST, BH);
    scatter_kernel<<<(N_EDGE + 255) / 256, 256, 0, stream>>>(esub, epred, eobj, HIST, OBJS);

    // degree binning: ROWIDX = rows grouped by degree
    bin_scan<<<1, 256, 0, stream>>>(BH, BOFF);
    bin_scatter<<<N_SBLK, 256, 0, stream>>>(OFFS, BOFF, ROWIDX);

    // Kt for all relations (single MFMA output)
    proj_mfma<<<(N_NODES + 127) / 128, 512, 0, stream>>>(XB, Ct, KT);

    // fused bilinear-dot + softmax + x-space aggregate (degree-matched rows)
    agg_fused<<<N_ROWS / 16, 256, 0, stream>>>(ROWIDX, OFFS, OBJS,
                                               (const uint_t*)KT, (const uint_t*)XB,
                                               (uint_t*)AGG);

    unify_mfma<<<(N_NODES + 63) / 64, 256, 0, stream>>>(AGG, Mb, out);
}

// Round 15
// 162.040 us; speedup vs baseline: 1.2203x; 1.2203x over previous
//
#include <hip/hip_runtime.h>

constexpr int N_NODES = 50000;
constexpr int N_REL   = 4;
constexpr int EMBD    = 128;
constexpr int N_HEAD  = 4;
constexpr int HS      = 32;
constexpr int N_EDGE  = 400000;
constexpr int N_ROWS  = N_REL * N_NODES;        // 200000 segment rows
constexpr int N_SBLK  = 196;                    // scan blocks (1024 rows each)

typedef __attribute__((ext_vector_type(8))) short bf16x8;
typedef __attribute__((ext_vector_type(4))) float f32x4;
typedef unsigned short ushort_t;
typedef unsigned int   uint_t;

__device__ __forceinline__ ushort_t f2b(float f) {
    unsigned int u = __float_as_uint(f);
    u += 0x7FFF + ((u >> 16) & 1);   // round-to-nearest-even
    return (ushort_t)(u >> 16);
}
__device__ __forceinline__ float lo_bf(uint_t u) {   // bf16 pair: low elem
    return __uint_as_float(u << 16);
}
__device__ __forceinline__ float hi_bf(uint_t u) {   // bf16 pair: high elem
    return __uint_as_float(u & 0xFFFF0000u);
}

// ---------------------------------------------------------------------------
// prep (fused): XB = bf16(x), HIST = 0, Ct = tokeys^T toqueries (per r,h),
// Mb = U·BD(tovals). KNOWN GOOD (r13).
// ---------------------------------------------------------------------------
__global__ __launch_bounds__(256) void prep_kernel(
    const float* __restrict__ x,
    const float* __restrict__ tk, const float* __restrict__ tq,
    const float* __restrict__ tv, const float* __restrict__ un,
    ushort_t* __restrict__ XB, int* __restrict__ HIST,
    ushort_t* __restrict__ Ct, ushort_t* __restrict__ Mb)
{
    int idx = blockIdx.x * 256 + threadIdx.x;      // grid 25320 = 6481920 threads
    if (idx < N_NODES * EMBD) {
        XB[idx] = f2b(x[idx]);
        if (idx < N_ROWS) HIST[idx] = 0;
    } else {
        int jj = idx - N_NODES * EMBD;             // < 81920
        if (jj < 16384) {
            int a = jj & 31, b = (jj >> 5) & 31, rh = jj >> 10;   // rh = r*4+h
            const float* tks = tk + rh * 1024;     // [s][a]
            const float* tqs = tq + rh * 1024;     // [s][b]
            float acc = 0.f;
            #pragma unroll
            for (int s = 0; s < 32; s++) acc += tks[s * 32 + a] * tqs[s * 32 + b];
            Ct[jj] = f2b(acc);                     // (rh*32 + b)*32 + a
        } else {
            int j  = jj - 16384;                   // Mb flat: [r][i][jc]
            int jc = j & 127, i = (j >> 7) & 127, r = j >> 14;
            int h = jc >> 5, k = jc & 31;
            const float* us  = un + ((size_t)(r * 128 + i)) * 128 + h * 32;
            const float* tvs = tv + (r * 4 + h) * 1024 + k;
            float acc = 0.f;
            #pragma unroll
            for (int s = 0; s < 32; s++) acc += us[s] * tvs[s * 32];
            Mb[j] = f2b(acc);
        }
    }
}

// ---------------------------------------------------------------------------
// MFMA projection: Kt[r][n][h*32+b] = sum_a Ct[r,h,b,a]*x[n,h*32+a].
// KNOWN GOOD (r12-13; fragment maps proven r5-13).
// ---------------------------------------------------------------------------
__global__ __launch_bounds__(512) void proj_mfma(
    const ushort_t* __restrict__ XB, const ushort_t* __restrict__ Ct,
    ushort_t* __restrict__ KT)
{
    __shared__ ushort_t xs[128 * 136];   // [node][k] bf16, stride 272B

    const int t    = threadIdx.x;        // 0..511
    const int lane = t & 63;
    const int w    = t >> 6;             // wave 0..7
    const int n0   = blockIdx.x * 128;

    {   // stage XB tile (bf16, 16B chunks)
        const uint4* x4 = (const uint4*)(XB + (size_t)n0 * 128);
        for (int idx = t; idx < 128 * 16; idx += 512) {
            int nn = idx >> 4, c = idx & 15;
            uint4 v = make_uint4(0, 0, 0, 0);
            if (n0 + nn < N_NODES) v = x4[idx];
            *(uint4*)&xs[nn * 136 + c * 8] = v;
        }
    }
    __syncthreads();

    const int row  = lane & 15;     // A node-row / B col / D col
    const int kg   = lane >> 4;     // k-group (8 elems each)
    const int rgrp = lane >> 4;     // D row-group

    #pragma unroll 1
    for (int r = 0; r < N_REL; r++) {
        f32x4 acc[8];
        #pragma unroll
        for (int f = 0; f < 8; f++) {
            const int h = f >> 1;
            bf16x8 a = *(const bf16x8*)&xs[(w * 16 + row) * 136 + h * 32 + kg * 8];
            const ushort_t* bp = Ct + (((r * 4 + h) * 32 + (f & 1) * 16 + row) * 32) + kg * 8;
            bf16x8 b = *(const bf16x8*)bp;
            acc[f] = __builtin_amdgcn_mfma_f32_16x16x32_bf16(
                         a, b, (f32x4){0.f, 0.f, 0.f, 0.f}, 0, 0, 0);
        }
        #pragma unroll
        for (int f = 0; f < 8; f++) {
            #pragma unroll
            for (int reg = 0; reg < 4; reg++) {
                int n = n0 + w * 16 + rgrp * 4 + reg;
                if (n < N_NODES)
                    KT[((size_t)r * N_NODES + n) * 128 + f * 16 + row] = f2b(acc[f][reg]);
            }
        }
    }
}

// ---------------------------------------------------------------------------
// CSR build: histogram -> 3-phase deterministic scan -> scatter. KNOWN GOOD
// (r9-13 structure; round-14 binning reverted — it cost locality).
// ---------------------------------------------------------------------------
__global__ __launch_bounds__(256) void hist_kernel(
    const int* __restrict__ esub, const int* __restrict__ epred, int* __restrict__ HIST)
{
    int e = blockIdx.x * 256 + threadIdx.x;
    if (e < N_EDGE) atomicAdd(&HIST[epred[e] * N_NODES + esub[e]], 1);
}

__global__ __launch_bounds__(256) void scan_p1(      // per-block totals
    const int* __restrict__ HIST, int* __restrict__ SUMS)
{
    int b = blockIdx.x, t = threadIdx.x;
    int base = b * 1024 + t * 4;
    int s = 0;
    #pragma unroll
    for (int k = 0; k < 4; k++) if (base + k < N_ROWS) s += HIST[base + k];
    __shared__ int red[256];
    red[t] = s; __syncthreads();
    for (int st = 128; st > 0; st >>= 1) {
        if (t < st) red[t] += red[t + st];
        __syncthreads();
    }
    if (t == 0) SUMS[b] = red[0];
}

__global__ __launch_bounds__(256) void scan_p2(      // scan the 196 totals
    const int* __restrict__ SUMS, int* __restrict__ SOFF, int* __restrict__ OFFS)
{
    int t = threadIdx.x;
    __shared__ int sh[256];
    int o = (t < N_SBLK) ? SUMS[t] : 0;
    sh[t] = o; __syncthreads();
    for (int st = 1; st < 256; st <<= 1) {
        int v = (t >= st) ? sh[t - st] : 0;
        __syncthreads();
        sh[t] += v;
        __syncthreads();
    }
    if (t < N_SBLK) SOFF[t] = sh[t] - o;             // exclusive
    if (t == 0)  OFFS[N_ROWS] = sh[255];             // total == N_EDGE
}

__global__ __launch_bounds__(256) void scan_p3(      // full exclusive scan (+CURSOR)
    const int* __restrict__ HIST, const int* __restrict__ SOFF,
    int* __restrict__ OFFS, int* __restrict__ CURSOR)
{
    int b = blockIdx.x, t = threadIdx.x;
    int base = b * 1024 + t * 4;
    int v[4], tot = 0;
    #pragma unroll
    for (int k = 0; k < 4; k++) {
        v[k] = (base + k < N_ROWS) ? HIST[base + k] : 0;
        tot += v[k];
    }
    __shared__ int sh[256];
    sh[t] = tot; __syncthreads();
    for (int st = 1; st < 256; st <<= 1) {
        int q = (t >= st) ? sh[t - st] : 0;
        __syncthreads();
        sh[t] += q;
        __syncthreads();
    }
    int run = SOFF[b] + (sh[t] - tot);
    #pragma unroll
    for (int k = 0; k < 4; k++) {
        if (base + k < N_ROWS) { OFFS[base + k] = run; CURSOR[base + k] = run; run += v[k]; }
    }
}

__global__ __launch_bounds__(256) void scatter_kernel(
    const int* __restrict__ esub, const int* __restrict__ epred, const int* __restrict__ eobj,
    int* __restrict__ CURSOR, int* __restrict__ OBJS)
{
    int e = blockIdx.x * 256 + threadIdx.x;
    if (e < N_EDGE) {
        int row = epred[e] * N_NODES + esub[e];
        int pos = atomicAdd(&CURSOR[row], 1);
        OBJS[pos] = eobj[e];                       // store obj, not edge id
    }
}

// ---------------------------------------------------------------------------
// FUSED dot+softmax+aggregate, HALF-WAVE per row (lanes 0-31 row 2w, lanes
// 32-63 row 2w+1 — ADJACENT rows, keeping r13's locality that r14's binning
// destroyed). Each lane owns 4 elems (uint2 = 8B; 32 lanes = one 256B row):
//  - head = 8-lane group -> butterfly is 3 shfl (was 4),
//  - ONE gather instruction fetches x_obj rows for TWO edges (one per half),
//  - ONE exp instruction serves both halves.
// 2-edge manual unroll per half: 2 independent chains per half in flight.
// Per-edge issue cost ~2x lower than r13's 16-lane layout. d0/d1 are
// half-uniform; shfl+exp run on all lanes (safe), accumulation is guarded.
// ---------------------------------------------------------------------------
__global__ __launch_bounds__(256) void agg_fused(
    const int* __restrict__ OFFS, const int* __restrict__ OBJS,
    const uint2* __restrict__ KT128, const uint2* __restrict__ XB128,
    uint2* __restrict__ AGG128)
{
    const int t    = threadIdx.x;
    const int lane = t & 63;
    const int l5   = lane & 31;                     // intra-half lane
    const int row  = (blockIdx.x * 4 + (t >> 6)) * 2 + (lane >> 5);  // grid 25000

    const int beg = OFFS[row], end = OFFS[row + 1]; // half-uniform
    const bool has = beg < end;

    float k0 = 0.f, k1 = 0.f, k2 = 0.f, k3 = 0.f;
    if (has) {
        uint2 ku = KT128[(unsigned)row * 32u + l5];
        k0 = lo_bf(ku.x); k1 = hi_bf(ku.x); k2 = lo_bf(ku.y); k3 = hi_bf(ku.y);
    }

    float a0 = 0.f, a1 = 0.f, a2 = 0.f, a3 = 0.f, seg = 0.f;
    int it = beg;
    while (__any(it < end)) {                       // wave-uniform loop bound
        const bool d0 = it < end;                   // half-uniform guards
        const bool d1 = it + 1 < end;
        uint2 xu0 = make_uint2(0u, 0u), xu1 = make_uint2(0u, 0u);
        if (d0) xu0 = XB128[(unsigned)OBJS[it] * 32u + l5];
        if (d1) xu1 = XB128[(unsigned)OBJS[it + 1] * 32u + l5];

        float x00 = lo_bf(xu0.x), x01 = hi_bf(xu0.x), x02 = lo_bf(xu0.y), x03 = hi_bf(xu0.y);
        float x10 = lo_bf(xu1.x), x11 = hi_bf(xu1.x), x12 = lo_bf(xu1.y), x13 = hi_bf(xu1.y);

        float p0 = k0 * x00 + k1 * x01 + k2 * x02 + k3 * x03;
        float p1 = k0 * x10 + k1 * x11 + k2 * x12 + k3 * x13;
        p0 += __shfl_xor(p0, 1, 64); p1 += __shfl_xor(p1, 1, 64);
        p0 += __shfl_xor(p0, 2, 64); p1 += __shfl_xor(p1, 2, 64);
        p0 += __shfl_xor(p0, 4, 64); p1 += __shfl_xor(p1, 4, 64);
        float ex0 = __expf(p0), ex1 = __expf(p1);

        int adv = 0;
        if (d0) { a0 += ex0 * x00; a1 += ex0 * x01; a2 += ex0 * x02; a3 += ex0 * x03; seg += ex0; adv = 1; }
        if (d1) { a0 += ex1 * x10; a1 += ex1 * x11; a2 += ex1 * x12; a3 += ex1 * x13; seg += ex1; adv = 2; }
        it += adv;
    }

    uint2 o = make_uint2(0u, 0u);
    if (has) {
        float inv = 1.0f / seg;
        o.x = (uint_t)f2b(a0 * inv) | ((uint_t)f2b(a1 * inv) << 16);
        o.y = (uint_t)f2b(a2 * inv) | ((uint_t)f2b(a3 * inv) << 16);
    }
    AGG128[(unsigned)row * 32u + l5] = o;
}

// ---------------------------------------------------------------------------
// out[n][i] = relu( sum_r sum_j M[r][i][j] * AGGX[r][n][j] )  — bf16 MFMA,
// fp32 accum. KNOWN GOOD (rounds 5-14); B = Mb (U·BD(tovals)).
// ---------------------------------------------------------------------------
__global__ __launch_bounds__(256) void unify_mfma(
    const ushort_t* __restrict__ AGG,
    const ushort_t* __restrict__ Ub, float* __restrict__ out)
{
    __shared__ ushort_t As[64 * 136];    // A tile: [node][k] bf16
    __shared__ ushort_t Bs[128 * 136];   // B tile: [i][k] bf16

    const int t    = threadIdx.x;
    const int lane = t & 63;
    const int w    = t >> 6;
    const int n0   = blockIdx.x * 64;

    f32x4 acc[8];
    #pragma unroll
    for (int f = 0; f < 8; f++) acc[f] = (f32x4){0.f, 0.f, 0.f, 0.f};

    for (int r = 0; r < N_REL; r++) {
        __syncthreads();

        {   // stage A: AGG[r][n0..n0+63][0..127] plain bf16 copy (16B chunks)
            const uint4* a4 = (const uint4*)(AGG + ((size_t)r * N_NODES + n0) * 128);
            for (int idx = t; idx < 64 * 16; idx += 256) {
                int nn = idx >> 4, c = idx & 15;
                uint4 v = make_uint4(0, 0, 0, 0);
                if (n0 + nn < N_NODES) v = a4[idx];
                *(uint4*)&As[nn * 136 + c * 8] = v;
            }
        }
        {   // stage B: Mb[r] straight copy (L2-hot)
            const uint4* u4 = (const uint4*)(Ub + (size_t)r * 128 * 128);
            for (int idx = t; idx < 128 * 16; idx += 256) {
                int i = idx >> 4, c = idx & 15;
                *(uint4*)&Bs[i * 136 + c * 8] = u4[idx];
            }
        }
        __syncthreads();

        const int row = lane & 15;     // A row / B col
        const int kg  = lane >> 4;     // k-group
        #pragma unroll
        for (int ks = 0; ks < 4; ks++) {
            const int kofs = ks * 32 + kg * 8;
            bf16x8 a = *(const bf16x8*)&As[(w * 16 + row) * 136 + kofs];
            #pragma unroll
            for (int f = 0; f < 8; f++) {
                bf16x8 b = *(const bf16x8*)&Bs[(f * 16 + row) * 136 + kofs];
                acc[f] = __builtin_amdgcn_mfma_f32_16x16x32_bf16(a, b, acc[f], 0, 0, 0);
            }
        }
    }

    const int col  = lane & 15;
    const int rgrp = lane >> 4;
    #pragma unroll
    for (int f = 0; f < 8; f++) {
        #pragma unroll
        for (int reg = 0; reg < 4; reg++) {
            int n = n0 + w * 16 + rgrp * 4 + reg;
            if (n < N_NODES)
                out[(size_t)n * 128 + f * 16 + col] = fmaxf(acc[f][reg], 0.f);
        }
    }
}

extern "C" void kernel_launch(void* const* d_in, const int* in_sizes, int n_in,
                              void* d_out, int out_size, void* d_ws, size_t ws_size,
                              hipStream_t stream)
{
    const float* x  = (const float*)d_in[0];
    const float* tk = (const float*)d_in[1];
    const float* tq = (const float*)d_in[2];
    const float* tv = (const float*)d_in[3];
    const float* un = (const float*)d_in[4];
    const int* esub  = (const int*)d_in[5];
    const int* epred = (const int*)d_in[6];
    const int* eobj  = (const int*)d_in[7];
    float* out = (float*)d_out;

    // Workspace layout (bytes), identical to round 12/13 (proven):
    //   KT:   [R][N][128] bf16 (Kt = Ct-projected x)     @ 0            (51,200,000)
    //   XB:   [N][128] bf16 (x cast — the gather target) @ 51,200,000   (12,800,000)
    //   AGG:  [R*N][128] bf16 (x-space aggregates)       @ 64,000,000   (51,200,000)
    //   HIST/CURSOR: [200000] int                        @ 115,200,000  (   800,000)
    //   SUMS: [196] int (pad 4096)                       @ 116,000,000  (     4,096)
    //   SOFF: [196] int (pad 4096)                       @ 116,004,096  (     4,096)
    //   OFFS: [200001] int                               @ 116,008,192  (   800,004 pad)
    //   OBJS: [400000] int                               @ 116,816,000  ( 1,600,000)
    //   Mb:   [R][128][128] bf16 (U·BD(tovals))          @ 118,416,000  (   131,072)
    //   Ct:   [R][H][32][32] bf16 (K^T Q bilinear)       @ 118,547,072  (    32,768)
    char* ws = (char*)d_ws;
    ushort_t* KT  = (ushort_t*)(ws);
    ushort_t* XB  = (ushort_t*)(ws + 51200000);
    ushort_t* AGG = (ushort_t*)(ws + 64000000);
    int*      HIST= (int*)     (ws + 115200000);   // doubles as CURSOR
    int*      SUMS= (int*)     (ws + 116000000);
    int*      SOFF= (int*)     (ws + 116004096);
    int*      OFFS= (int*)     (ws + 116008192);
    int*      OBJS= (int*)     (ws + 116816000);
    ushort_t* Mb  = (ushort_t*)(ws + 118416000);
    ushort_t* Ct  = (ushort_t*)(ws + 118547072);

    // prep (fused): x cast + HIST zero + Ct/Mb small-matrix products
    prep_kernel<<<(N_NODES * EMBD + 81920) / 256, 256, 0, stream>>>(
        x, tk, tq, tv, un, XB, HIST, Ct, Mb);

    // CSR build
    hist_kernel<<<(N_EDGE + 255) / 256, 256, 0, stream>>>(esub, epred, HIST);
    scan_p1<<<N_SBLK, 256, 0, stream>>>(HIST, SUMS);
    scan_p2<<<1, 256, 0, stream>>>(SUMS, SOFF, OFFS);
    scan_p3<<<N_SBLK, 256, 0, stream>>>(HIST, SOFF, OFFS, HIST);  // OFFS + CURSOR
    scatter_kernel<<<(N_EDGE + 255) / 256, 256, 0, stream>>>(esub, epred, eobj, HIST, OBJS);

    // Kt for all relations (single MFMA output)
    proj_mfma<<<(N_NODES + 127) / 128, 512, 0, stream>>>(XB, Ct, KT);

    // fused bilinear-dot + softmax + x-space aggregate (half-wave per row,
    // 2-edge unroll, sequential row assignment for locality)
    agg_fused<<<N_ROWS / 8, 256, 0, stream>>>(OFFS, OBJS,
                                              (const uint2*)KT, (const uint2*)XB,
                                              (uint2*)AGG);

    unify_mfma<<<(N_NODES + 63) / 64, 256, 0, stream>>>(AGG, Mb, out);
}